// Round 9
// baseline (24.276 us; speedup 1.0000x reference)
//
#include <hip/hip_runtime.h>
#include <math.h>

#define EPSN 1e-12f

typedef __attribute__((ext_vector_type(8))) __bf16 bf16x8;
typedef __attribute__((ext_vector_type(8))) short short8;
typedef __attribute__((ext_vector_type(4))) float floatx4;

static __device__ __forceinline__ unsigned short f2bf(float f) {
    return __builtin_bit_cast(unsigned short, (__bf16)f);
}

// ---------------------------------------------------------------------------
// Single fused kernel. grid 512 = (m-half h = gid>>8) x (bc-group of 8).
// 256 threads, 2 blocks/CU.
//  prefetch: 16 x-dwordx4 into regs (latency hidden under transpose(0)).
//  transpose_step(e): At_lds[64m][128n] = bf16(A[e][n][m0+m]) (XOR-swizzled)
//                     + column ssq partials -> red[4][64].  L2-hot, in-block.
//  phase 1: xw[4e][32r][128n] = bf16( x @ W[e] ), W via uniform scalar loads.
//  per e: phase 2: all 4 waves on e; wave w covers m = w*16+cl, 32 r.
//         8 MFMA (2rt x 4ks); epilogue: rnorm (from red) * relu, float4 store.
// ---------------------------------------------------------------------------
__global__ __launch_bounds__(256, 2)
void gcn_fused(const float* __restrict__ x, const float* __restrict__ A,
               const float* __restrict__ W, float* __restrict__ out) {
    __shared__ __align__(16) unsigned char xw[32768];  // [4e][32r][128n] bf16, swz
    __shared__ __align__(16) unsigned char at[16384];  // [64m][128n] bf16, swz
    __shared__ float red[4][64];                       // ssq partials

    const int t   = threadIdx.x;
    const int gid = blockIdx.x;
    const int h   = gid >> 8;          // m-half; g and g+256 share x, same XCD
    const int bc0 = (gid & 255) * 8;
    const int m0  = h * 64;

    const int w  = t >> 6;             // wave 0..3
    const int l  = t & 63;
    const int cl = l & 15;
    const int lg = l >> 4;
    const int ml = t & 63;             // transpose: m-lane
    const int ng = t >> 6;             // transpose: n-group

    // ---- prefetch x: 4 (bcl,n) pairs, 16 global_load_dwordx4 ----
    float4 xf[4][4];
    #pragma unroll
    for (int p = 0; p < 4; ++p) {
        int pair = p * 256 + t;
        int bcl = pair >> 7, n = pair & 127;
        const float4* xp = (const float4*)(x + ((size_t)(bc0 + bcl) * 128 + n) * 16);
        xf[p][0] = xp[0]; xf[p][1] = xp[1]; xf[p][2] = xp[2]; xf[p][3] = xp[3];
    }

    // ---- transpose step: A[e][n][m0+ml] -> at[ml][n] bf16 (swizzled) + ssq ----
    auto transpose_step = [&](int e) {
        const float* Ae = A + e * 16384 + m0 + ml;
        float ssq = 0.f;
        #pragma unroll
        for (int it = 0; it < 4; ++it) {
            int n0 = it * 32 + ng * 8;
            float v[8];
            #pragma unroll
            for (int j = 0; j < 8; ++j) v[j] = Ae[(size_t)(n0 + j) * 128];
            unsigned short hs[8] __attribute__((aligned(16)));
            #pragma unroll
            for (int j = 0; j < 8; ++j) { ssq += v[j] * v[j]; hs[j] = f2bf(v[j]); }
            int byteoff = ((ml << 8) + n0 * 2) ^ ((ml & 7) << 4);
            *(short8*)(at + byteoff) = *(const short8*)hs;
        }
        red[ng][ml] = ssq;
    };

    transpose_step(0);

    // ---- phase 1: xw[e][r=(bcl,o)][n] = bf16( sum_f x*W ) ----
    #pragma unroll 1
    for (int e = 0; e < 4; ++e) {
        const float* We = W + e * 64;      // wave-uniform -> scalar loads/SGPR
        #pragma unroll
        for (int p = 0; p < 4; ++p) {
            int bcl = p * 2 + (t >> 7);
            int n   = t & 127;
            float a0 = 0.f, a1 = 0.f, a2 = 0.f, a3 = 0.f;
            #pragma unroll
            for (int f = 0; f < 16; ++f) {
                float xv = ((const float*)&xf[p][f >> 2])[f & 3];
                a0 += xv * We[f * 4 + 0];
                a1 += xv * We[f * 4 + 1];
                a2 += xv * We[f * 4 + 2];
                a3 += xv * We[f * 4 + 3];
            }
            float av[4] = {a0, a1, a2, a3};
            #pragma unroll
            for (int o = 0; o < 4; ++o) {
                int r = bcl * 4 + o;
                int byteoff = (((e * 32 + r) << 8) + n * 2) ^ ((r & 7) << 4);
                *(unsigned short*)(xw + byteoff) = f2bf(av[o]);
            }
        }
    }
    __syncthreads();

    // ---- per-e: phase 2 + epilogue ----
    #pragma unroll 1
    for (int e = 0; e < 4; ++e) {
        // A-operand frags from xw[e] (R7-verified pattern)
        bf16x8 af[2][4];
        #pragma unroll
        for (int rt = 0; rt < 2; ++rt)
            #pragma unroll
            for (int ks = 0; ks < 4; ++ks) {
                int row = rt * 16 + cl;
                int byteoff = (((e * 32 + row) << 8) + (ks * 32 + lg * 8) * 2)
                              ^ ((row & 7) << 4);
                af[rt][ks] = __builtin_bit_cast(bf16x8, *(const short8*)(xw + byteoff));
            }
        // B-operand frags from at (rows mrow = w*16+cl)
        const int mrow = w * 16 + cl;
        bf16x8 bfr[4];
        #pragma unroll
        for (int ks = 0; ks < 4; ++ks) {
            int byteoff = ((mrow << 8) + (ks * 32 + lg * 8) * 2) ^ ((mrow & 7) << 4);
            bfr[ks] = __builtin_bit_cast(bf16x8, *(const short8*)(at + byteoff));
        }

        floatx4 acc0 = {0.f, 0.f, 0.f, 0.f};
        floatx4 acc1 = {0.f, 0.f, 0.f, 0.f};
        #pragma unroll
        for (int ks = 0; ks < 4; ++ks) {
            acc0 = __builtin_amdgcn_mfma_f32_16x16x32_bf16(af[0][ks], bfr[ks], acc0, 0, 0, 0);
            acc1 = __builtin_amdgcn_mfma_f32_16x16x32_bf16(af[1][ks], bfr[ks], acc1, 0, 0, 0);
        }

        // rnorm for (e, m0+mrow) from in-block ssq partials
        float s = red[0][mrow] + red[1][mrow] + red[2][mrow] + red[3][mrow];
        float rn = 1.0f / fmaxf(sqrtf(s), EPSN);

        // D: col=cl (m-offset), row=lg*4+j -> r = rt*16+lg*4+j -> bcl=rt*4+lg, o=j
        #pragma unroll
        for (int rt = 0; rt < 2; ++rt) {
            floatx4 a = rt ? acc1 : acc0;
            int bc = bc0 + rt * 4 + lg;
            int b = bc >> 4, c = bc & 15;
            float4 o4;
            o4.x = fmaxf(a[0] * rn, 0.f);
            o4.y = fmaxf(a[1] * rn, 0.f);
            o4.z = fmaxf(a[2] * rn, 0.f);
            o4.w = fmaxf(a[3] * rn, 0.f);
            ((float4*)out)[(size_t)(b * 64 + e * 16 + c) * 128 + m0 + mrow] = o4;
        }

        // stage next e's At (protect at/red readers first)
        if (e < 3) {
            __syncthreads();
            transpose_step(e + 1);
            __syncthreads();
        }
    }
}

extern "C" void kernel_launch(void* const* d_in, const int* in_sizes, int n_in,
                              void* d_out, int out_size, void* d_ws, size_t ws_size,
                              hipStream_t stream) {
    const float* x = (const float*)d_in[0];   // [128,16,128,16]
    const float* A = (const float*)d_in[1];   // [4,128,128]
    const float* W = (const float*)d_in[2];   // [4,16,4]
    float* out = (float*)d_out;               // [128,64,128,4]

    gcn_fused<<<512, 256, 0, stream>>>(x, A, W, out);
}

// Round 11
// 20.643 us; speedup vs baseline: 1.1760x; 1.1760x over previous
//
#include <hip/hip_runtime.h>
#include <math.h>

#define EPSN 1e-12f

typedef __attribute__((ext_vector_type(8))) __bf16 bf16x8;
typedef __attribute__((ext_vector_type(8))) short short8;
typedef __attribute__((ext_vector_type(4))) float floatx4;

static __device__ __forceinline__ unsigned short f2bf(float f) {
    return __builtin_bit_cast(unsigned short, (__bf16)f);
}

// ---------------------------------------------------------------------------
// Producer (all paths verified in R6/R8):
//   blocks 0..1023 : XW[e][bc*4+o][n] = bf16( sum_f x[bc][n][f] W[e][f][o] )
//   blocks 1024..1087: At[e][m][n] = bf16( A[e][n][m] )   (raw transpose)
//   blocks 1088..1091: rnorm[e][m] = 1/max(||A[e][:][m]||, eps)
// ---------------------------------------------------------------------------
__global__ __launch_bounds__(256)
void produce_kernel(const float* __restrict__ x, const float* __restrict__ A,
                    const float* __restrict__ W, unsigned short* __restrict__ XW,
                    unsigned short* __restrict__ At, float* __restrict__ rnorm) {
    __shared__ float Wl[256];
    __shared__ float Als[32][33];
    const int t = threadIdx.x, bid = blockIdx.x;

    if (bid >= 1024) {
        int pb = bid - 1024;
        if (pb < 64) {   // ---- raw transpose (R8-verified) ----
            const int e = pb >> 4, n0 = ((pb >> 2) & 3) * 32, m0 = (pb & 3) * 32;
            const float* Ae = A + e * 16384;
            #pragma unroll
            for (int i = 0; i < 4; ++i) {
                int nl = i * 8 + (t >> 5), ml = t & 31;
                Als[nl][ml] = Ae[(n0 + nl) * 128 + m0 + ml];   // coalesced in m
            }
            __syncthreads();
            int ml = t >> 3, nc = (t & 7) * 4;
            unsigned short hs[4] __attribute__((aligned(8)));
            #pragma unroll
            for (int j = 0; j < 4; ++j) hs[j] = f2bf(Als[nc + j][ml]);
            *(unsigned long long*)(At + ((size_t)(e * 128 + m0 + ml) * 128 + n0 + nc)) =
                *(const unsigned long long*)hs;
        } else {         // ---- column norms (R8-verified) ----
            int e = pb - 64;
            if (t < 128) {
                const float* Ae = A + e * 16384 + t;
                float s = 0.f;
                #pragma unroll 8
                for (int n = 0; n < 128; ++n) { float v = Ae[n * 128]; s += v * v; }
                rnorm[e * 128 + t] = 1.0f / fmaxf(sqrtf(s), EPSN);
            }
        }
        return;
    }

    // ---- XW path (R6-verified) ----
    if (t < 64) { float4 w4 = ((const float4*)W)[t]; *(float4*)&Wl[t * 4] = w4; }
    const int bc = bid * 2 + (t >> 7);
    const int n  = t & 127;
    const float4* xp = (const float4*)(x + ((size_t)bc * 128 + n) * 16);
    float xs[16];
    #pragma unroll
    for (int q = 0; q < 4; ++q) {
        float4 v = xp[q];
        xs[q * 4 + 0] = v.x; xs[q * 4 + 1] = v.y;
        xs[q * 4 + 2] = v.z; xs[q * 4 + 3] = v.w;
    }
    __syncthreads();
    #pragma unroll 1
    for (int e = 0; e < 4; ++e) {
        float a0 = 0.f, a1 = 0.f, a2 = 0.f, a3 = 0.f;
        #pragma unroll
        for (int f = 0; f < 16; ++f) {
            float xv = xs[f];
            float4 w = *(const float4*)&Wl[(e * 16 + f) * 4];
            a0 += xv * w.x; a1 += xv * w.y; a2 += xv * w.z; a3 += xv * w.w;
        }
        size_t base = ((size_t)e * 8192 + (size_t)bc * 4) * 128 + n;
        XW[base      ] = f2bf(a0);
        XW[base + 128] = f2bf(a1);
        XW[base + 256] = f2bf(a2);
        XW[base + 384] = f2bf(a3);
    }
}

// ---------------------------------------------------------------------------
// Consumer: grid 512 = (e = gid>>7) x (bc-group of 16 = gid&127). 256 thr.
// Stage full At[e] (32 KB) -> LDS, XOR-swizzled; each wave holds ALL 32
// B-fragments (128m x 128K) in registers + 4 A-fragments (16r x 128K) ->
// 32 MFMA entirely register-fed. Epilogue: rnorm * relu, coalesced stores.
// ---------------------------------------------------------------------------
__global__ __launch_bounds__(256, 2)
void gemm_kernel(const unsigned short* __restrict__ XW,
                 const unsigned short* __restrict__ At,
                 const float* __restrict__ rnorm, float* __restrict__ out) {
    __shared__ __align__(16) unsigned char atl[32768];   // [128m][16 slots], swz

    const int t   = threadIdx.x;
    const int gid = blockIdx.x;
    const int e   = gid >> 7;
    const int bc0 = (gid & 127) * 16;

    const int w  = t >> 6;     // wave 0..3: r-tile
    const int l  = t & 63;
    const int cl = l & 15;
    const int lg = l >> 4;

    // ---- issue af global loads first (overlap with staging) ----
    const int rg = bc0 * 4 + w * 16 + cl;     // global XW row for this lane
    const unsigned short* xwp = XW + ((size_t)e * 8192 + rg) * 128 + lg * 8;
    bf16x8 af[4];
    #pragma unroll
    for (int ks = 0; ks < 4; ++ks)
        af[ks] = __builtin_bit_cast(bf16x8, *(const short8*)(xwp + ks * 32));

    // rnorm prefetch (8 values per lane: m = mt*16+cl)
    float rn[8];
    #pragma unroll
    for (int mt = 0; mt < 8; ++mt) rn[mt] = rnorm[e * 128 + mt * 16 + cl];

    // ---- stage At[e] -> LDS (b128 units; slot s16 XOR-swizzled by m&7) ----
    {
        const short8* src = (const short8*)(At + (size_t)e * 16384);
        #pragma unroll
        for (int i = 0; i < 8; ++i) {
            int idx = i * 256 + t;            // 0..2047 (16B units)
            int m = idx >> 4, s16 = idx & 15;
            short8 v = src[idx];
            *(short8*)(atl + ((m << 8) | ((s16 ^ (m & 7)) << 4))) = v;
        }
    }
    __syncthreads();

    // ---- load ALL 32 B-fragments into registers ----
    bf16x8 bfr[8][4];
    #pragma unroll
    for (int mt = 0; mt < 8; ++mt) {
        int m = mt * 16 + cl;
        #pragma unroll
        for (int ks = 0; ks < 4; ++ks) {
            int slot = (ks * 4 + lg) ^ (m & 7);
            bfr[mt][ks] = __builtin_bit_cast(bf16x8,
                *(const short8*)(atl + ((m << 8) | (slot << 4))));
        }
    }

    // ---- 32 MFMA, fully register-fed; 8 independent acc chains ----
    floatx4 acc[8];
    #pragma unroll
    for (int mt = 0; mt < 8; ++mt) acc[mt] = (floatx4){0.f, 0.f, 0.f, 0.f};
    #pragma unroll
    for (int ks = 0; ks < 4; ++ks)
        #pragma unroll
        for (int mt = 0; mt < 8; ++mt)
            acc[mt] = __builtin_amdgcn_mfma_f32_16x16x32_bf16(
                af[ks], bfr[mt][ks], acc[mt], 0, 0, 0);

    // ---- epilogue: D col=cl (m-off), row=lg*4+q -> r = w*16+lg*4+q
    //      -> bc = bc0 + w*4 + lg, o = q.  rnorm * relu, float4 stores.
    const int bc = bc0 + w * 4 + lg;
    const int b = bc >> 4, c = bc & 15;
    float4* outp = (float4*)out + ((size_t)(b * 64 + e * 16 + c) * 128);
    #pragma unroll
    for (int mt = 0; mt < 8; ++mt) {
        float r = rn[mt];
        float4 o4;
        o4.x = fmaxf(acc[mt][0] * r, 0.f);
        o4.y = fmaxf(acc[mt][1] * r, 0.f);
        o4.z = fmaxf(acc[mt][2] * r, 0.f);
        o4.w = fmaxf(acc[mt][3] * r, 0.f);
        outp[mt * 16 + cl] = o4;
    }
}

extern "C" void kernel_launch(void* const* d_in, const int* in_sizes, int n_in,
                              void* d_out, int out_size, void* d_ws, size_t ws_size,
                              hipStream_t stream) {
    const float* x = (const float*)d_in[0];   // [128,16,128,16]
    const float* A = (const float*)d_in[1];   // [4,128,128]
    const float* W = (const float*)d_in[2];   // [4,16,4]
    float* out = (float*)d_out;               // [128,64,128,4]
    unsigned short* At = (unsigned short*)d_ws;                    // 128 KB
    float* rnorm = (float*)((char*)d_ws + 131072);                 // 2 KB
    unsigned short* XW = (unsigned short*)((char*)d_ws + 139264);  // 8.4 MB

    produce_kernel<<<1092, 256, 0, stream>>>(x, A, W, XW, At, rnorm);
    gemm_kernel<<<512, 256, 0, stream>>>(XW, At, rnorm, out);
}